// Round 4
// baseline (328.335 us; speedup 1.0000x reference)
//
#include <hip/hip_runtime.h>

#define B 16
#define N 2048
#define F 64
#define E 24576   // edges per batch (N*M, M=12)
#define C 128     // bond channels

typedef unsigned int uint32;
typedef unsigned short ushort16;
typedef float fvec4 __attribute__((ext_vector_type(4)));
typedef int   ivec2 __attribute__((ext_vector_type(2)));

// ws layout (float units):
//   cnt     : int[B][N][2]        @ 0       (65536)
//   denom   : float[B][C]         @ 65536   (2048)
//   nodew   : float[B][2][C]      @ 67584   (4096)   Σ cnt_h·P_h  per (b,half,c)
//   nodesq  : float[B][C]         @ 71680   (2048)   Σ cnt·P²     per (b,c)
//   stats   : float[2][C]         @ 73728   (256)    sc2 | sh2 (exp2-folded BN affine)
//   P(bf16) : ushort[B][N][256]   @ 73984   (16 MB)
// zero region: cnt+denom+nodew+nodesq = 73728 floats = 294912 bytes

__device__ __forceinline__ ushort16 f2bf(float f) {
    uint32 u = __float_as_uint(f);
    u += 0x7fffu + ((u >> 16) & 1u);   // RNE (finite, no NaN possible here)
    return (ushort16)(u >> 16);
}
__device__ __forceinline__ float bf_lo(uint32 v) { return __uint_as_float(v << 16); }
__device__ __forceinline__ float bf_hi(uint32 v) { return __uint_as_float(v & 0xffff0000u); }

// 64 blocks (4 per batch, XCD-pinned via bid&15): LDS histogram then one
// XCD-local global atomic per nonzero bin (~250K atomics vs 786K before).
__global__ __launch_bounds__(256) void k_count(const int* __restrict__ adj,
                                               int* __restrict__ cnt) {
    __shared__ int h[N * 2];
    int t = threadIdx.x;
    for (int i = t; i < N * 2; i += 256) h[i] = 0;
    __syncthreads();
    int b = blockIdx.x & 15;
    int part = blockIdx.x >> 4;          // 0..3, 12288 entries each
    const int* ab = adj + (size_t)b * E * 2 + part * 12288;
    for (int i = t; i < 12288; i += 256) {
        int n = ab[i];
        atomicAdd(&h[n * 2 + (i & 1)], 1);   // parity preserved: 12288 even
    }
    __syncthreads();
    for (int i = t; i < N * 2; i += 256) {
        int v = h[i];
        if (v) atomicAdd(&cnt[b * N * 2 + i], v);
    }
}

__global__ __launch_bounds__(256) void k_denom(const float* __restrict__ atom,
                                               const int* __restrict__ cnt,
                                               float* __restrict__ denom) {
    // grid = B*16 blocks (128 nodes each); b pinned to XCD via bid&15
    int bid = blockIdx.x;
    int b = bid & 15;
    int chunk = bid >> 4;         // 0..15
    int t = threadIdx.x;
    int ch = t & 127;             // input channel 0..127
    int sub = t >> 7;             // 0/1 : 64-node subchunk
    int half = ch >> 6;
    int f = ch & 63;
    float s = 0.f;
    int n0 = chunk * 128 + sub * 64;
    for (int j = 0; j < 64; ++j) {
        int n = n0 + j;
        float cf = (float)cnt[(b * N + n) * 2 + half];
        s = fmaf(cf, fabsf(atom[(b * N + n) * 64 + f]), s);
    }
    __shared__ float sd[256];
    sd[t] = s;
    __syncthreads();
    if (t < 128) atomicAdd(&denom[b * C + ch], sd[t] + sd[t + 128]);
}

__global__ __launch_bounds__(256, 2) void k_p(const float* __restrict__ atom,
                                              const float* __restrict__ W,
                                              const float* __restrict__ denom,
                                              const int* __restrict__ cnt,
                                              ushort16* __restrict__ P,
                                              float* __restrict__ nodew,
                                              float* __restrict__ nodesq) {
    // grid = B*32 blocks, 64 node-rows each; b = bid&15 (XCD pin matches k_out)
    // thread: (half, output chans c & c+64, row subrange sub*32..+32)
    int bid = blockIdx.x;
    int b = bid & 15;
    int chunk = bid >> 4;         // 0..31
    int t = threadIdx.x;
    int cp = t & 127;
    int half = cp >> 6;           // which P (P0/P1)
    int c = cp & 63;              // output channels c, c+64
    int sub = t >> 7;             // row subrange

    __shared__ float invd[128];
    __shared__ float A2[64 * 128];
    __shared__ float cnts[2][64];

    if (t < 128) invd[t] = 1.0f / fmaxf(denom[b * C + t], 1e-12f);
    int nbase = chunk * 64;
    if (t < 128) {
        int h = t >> 6, r = t & 63;
        cnts[h][r] = (float)cnt[(b * N + nbase + r) * 2 + h];
    }
    __syncthreads();

    // stage scaled A tile: row-major [row][lo(64)|hi(64)]
    for (int i = t; i < 64 * 128; i += 256) {
        int r = i >> 7, col = i & 127;
        float a = atom[(b * N + nbase + r) * 64 + (col & 63)];
        A2[i] = a * invd[col];
    }

    // W columns for (half, c) and (half, c+64) in registers
    float wreg0[64], wreg1[64];
#pragma unroll
    for (int f = 0; f < 64; ++f) {
        wreg0[f] = W[(half * 64 + f) * 128 + c];
        wreg1[f] = W[(half * 64 + f) * 128 + c + 64];
    }

    __syncthreads();

    float s1a = 0.f, s2a = 0.f, s1b = 0.f, s2b = 0.f;
    int r0 = sub * 32;
    for (int r = r0; r < r0 + 32; ++r) {
        const float* a = &A2[r * 128 + half * 64];
        float acc0 = 0.f, acc1 = 0.f;
#pragma unroll
        for (int f = 0; f < 64; f += 4) {
            float4 av = *(const float4*)(a + f);
            acc0 = fmaf(av.x, wreg0[f], acc0);
            acc0 = fmaf(av.y, wreg0[f + 1], acc0);
            acc0 = fmaf(av.z, wreg0[f + 2], acc0);
            acc0 = fmaf(av.w, wreg0[f + 3], acc0);
            acc1 = fmaf(av.x, wreg1[f], acc1);
            acc1 = fmaf(av.y, wreg1[f + 1], acc1);
            acc1 = fmaf(av.z, wreg1[f + 2], acc1);
            acc1 = fmaf(av.w, wreg1[f + 3], acc1);
        }
        float cw = cnts[half][r];
        s1a = fmaf(cw, acc0, s1a);
        s2a = fmaf(cw * acc0, acc0, s2a);
        s1b = fmaf(cw, acc1, s1b);
        s2b = fmaf(cw * acc1, acc1, s2b);
        // row layout: ushort[256] = [P0 ch0..127 | P1 ch0..127]
        size_t base = ((size_t)(b * N + nbase + r)) * 256 + half * 128;
        P[base + c]      = f2bf(acc0);
        P[base + c + 64] = f2bf(acc1);
    }
    atomicAdd(&nodew[b * 256 + half * 128 + c],      s1a);
    atomicAdd(&nodew[b * 256 + half * 128 + c + 64], s1b);
    atomicAdd(&nodesq[b * 128 + c],      s2a);
    atomicAdd(&nodesq[b * 128 + c + 64], s2b);
}

// 1 block, 128 threads: finalize BN affine once (was redundantly recomputed by
// all 768 k_out blocks, a serial 16-iter L2-latency chain at each block head).
// Folds 2*log2(e) so k_out's tanh is 1 - 2*rcp(exp2(d*sc2 + sh2) + 1).
__global__ __launch_bounds__(128) void k_stats(const float* __restrict__ nodew,
                                               const float* __restrict__ nodesq,
                                               const float* __restrict__ gamma,
                                               const float* __restrict__ beta,
                                               float* __restrict__ st) {
    int cch = threadIdx.x;    // 0..127
    float m = 0.f, q = 0.f;
    const float invE = 1.0f / (float)E;
#pragma unroll
    for (int b2 = 0; b2 < B; ++b2) {
        float S0 = nodew[b2 * 256 + cch];
        float S1 = nodew[b2 * 256 + 128 + cch];
        m += S0 + S1;
        // Σ_e d² = Σ cnt·P² + 2·Σ_e P0[n0]P1[n1]; cross ≈ S0·S1/E (var ≪ eps)
        q += nodesq[b2 * 128 + cch] + 2.0f * S0 * S1 * invE;
    }
    const float inv = 1.0f / (float)(B * E);
    float mean_d = m * inv;
    float var = fmaxf(q * inv - mean_d * mean_d, 0.f);
    float sc = gamma[cch] * rsqrtf(var + 1e-5f);
    float sh = beta[cch] - mean_d * sc;        // linear bias cancels in BN
    const float C2 = 2.8853900817779268f;      // 2*log2(e): exp(2x) == exp2(C2*x)
    st[cch]       = sc * C2;
    st[128 + cch] = sh * C2;
}

__global__ __launch_bounds__(256) void k_out(const ivec2* __restrict__ adj2,
                                             const uint4* __restrict__ Pu4,
                                             const float* __restrict__ st,
                                             fvec4* __restrict__ out4) {
    // grid = 768 = 16 b * 48 chunks (512 edges each); b = bid&15 (XCD pin)
    // 16 lanes per edge, 8 channels per lane (uint4 gathers = 256B/segment)
    int bid = blockIdx.x;
    int b = bid & 15;
    int chunk = bid >> 4;
    int t = threadIdx.x;
    __shared__ ivec2 eadj[512];

    int e0 = chunk * 512;
    const ivec2* ab = &adj2[(size_t)b * E + e0];
    eadj[t]       = __builtin_nontemporal_load(&ab[t]);
    eadj[t + 256] = __builtin_nontemporal_load(&ab[t + 256]);

    int c8 = t & 15;              // channel octet 0..15 (ch 8*c8 .. 8*c8+7)
    int eg = t >> 4;              // edge slot 0..15
    // exp2-folded BN affine (1 KiB, L2-broadcast across all blocks)
    float4 sca = *(const float4*)(st + c8 * 8);
    float4 scb = *(const float4*)(st + c8 * 8 + 4);
    float4 sha = *(const float4*)(st + 128 + c8 * 8);
    float4 shb = *(const float4*)(st + 128 + c8 * 8 + 4);
    __syncthreads();

#pragma unroll 2
    for (int i = 0; i < 32; ++i) {
        int ei = i * 16 + eg;
        ivec2 nn = eadj[ei];
        uint4 v0 = Pu4[((size_t)(b * N + nn.x)) * 32 + c8];        // P0 octet
        uint4 v1 = Pu4[((size_t)(b * N + nn.y)) * 32 + 16 + c8];   // P1 octet
        float d0 = bf_lo(v0.x) + bf_lo(v1.x);
        float d1 = bf_hi(v0.x) + bf_hi(v1.x);
        float d2 = bf_lo(v0.y) + bf_lo(v1.y);
        float d3 = bf_hi(v0.y) + bf_hi(v1.y);
        float d4 = bf_lo(v0.z) + bf_lo(v1.z);
        float d5 = bf_hi(v0.z) + bf_hi(v1.z);
        float d6 = bf_lo(v0.w) + bf_lo(v1.w);
        float d7 = bf_hi(v0.w) + bf_hi(v1.w);
        float x0 = fmaf(d0, sca.x, sha.x);
        float x1 = fmaf(d1, sca.y, sha.y);
        float x2 = fmaf(d2, sca.z, sha.z);
        float x3 = fmaf(d3, sca.w, sha.w);
        float x4 = fmaf(d4, scb.x, shb.x);
        float x5 = fmaf(d5, scb.y, shb.y);
        float x6 = fmaf(d6, scb.z, shb.z);
        float x7 = fmaf(d7, scb.w, shb.w);
        // tanh(x) = 1 - 2/(exp2(x') + 1), x' = 2*log2e*x folded into sc/sh
        fvec4 oa, ob;
        oa.x = fmaf(-2.0f, __builtin_amdgcn_rcpf(__builtin_amdgcn_exp2f(x0) + 1.0f), 1.0f);
        oa.y = fmaf(-2.0f, __builtin_amdgcn_rcpf(__builtin_amdgcn_exp2f(x1) + 1.0f), 1.0f);
        oa.z = fmaf(-2.0f, __builtin_amdgcn_rcpf(__builtin_amdgcn_exp2f(x2) + 1.0f), 1.0f);
        oa.w = fmaf(-2.0f, __builtin_amdgcn_rcpf(__builtin_amdgcn_exp2f(x3) + 1.0f), 1.0f);
        ob.x = fmaf(-2.0f, __builtin_amdgcn_rcpf(__builtin_amdgcn_exp2f(x4) + 1.0f), 1.0f);
        ob.y = fmaf(-2.0f, __builtin_amdgcn_rcpf(__builtin_amdgcn_exp2f(x5) + 1.0f), 1.0f);
        ob.z = fmaf(-2.0f, __builtin_amdgcn_rcpf(__builtin_amdgcn_exp2f(x6) + 1.0f), 1.0f);
        ob.w = fmaf(-2.0f, __builtin_amdgcn_rcpf(__builtin_amdgcn_exp2f(x7) + 1.0f), 1.0f);
        size_t obase = ((size_t)(b * E + e0 + ei)) * 32 + c8 * 2;
        __builtin_nontemporal_store(oa, &out4[obase]);
        __builtin_nontemporal_store(ob, &out4[obase + 1]);
    }
}

extern "C" void kernel_launch(void* const* d_in, const int* in_sizes, int n_in,
                              void* d_out, int out_size, void* d_ws, size_t ws_size,
                              hipStream_t stream) {
    const float* atom  = (const float*)d_in[0];
    const int*   adj   = (const int*)d_in[1];
    const float* W     = (const float*)d_in[2];
    // d_in[3] = bias: cancels exactly in BatchNorm -> unused
    const float* gamma = (const float*)d_in[4];
    const float* beta  = (const float*)d_in[5];
    float* out = (float*)d_out;
    float* ws  = (float*)d_ws;

    int*      cnt    = (int*)ws;
    float*    denom  = ws + 65536;
    float*    nodew  = ws + 67584;
    float*    nodesq = ws + 71680;
    float*    st     = ws + 73728;
    ushort16* P      = (ushort16*)(ws + 73984);

    (void)hipMemsetAsync(d_ws, 0, 294912, stream);         // cnt+denom+nodew+nodesq
    k_count<<<64,   256, 0, stream>>>(adj, cnt);
    k_denom<<<256,  256, 0, stream>>>(atom, cnt, denom);
    k_p    <<<512,  256, 0, stream>>>(atom, W, denom, cnt, P, nodew, nodesq);
    k_stats<<<1,    128, 0, stream>>>(nodew, nodesq, gamma, beta, st);
    k_out  <<<768,  256, 0, stream>>>((const ivec2*)adj, (const uint4*)P, st, (fvec4*)out);
}

// Round 5
// 289.792 us; speedup vs baseline: 1.1330x; 1.1330x over previous
//
#include <hip/hip_runtime.h>

#define B 16
#define N 2048
#define F 64
#define E 24576   // edges per batch (N*M, M=12)
#define C 128     // bond channels

typedef unsigned int uint32;
typedef unsigned short ushort16;
typedef float fvec4 __attribute__((ext_vector_type(4)));
typedef int   ivec2 __attribute__((ext_vector_type(2)));

// ws layout (float units):
//   cnt     : int[B][N][2]        @ 0       (65536)
//   denom   : float[B][C]         @ 65536   (2048)
//   nodew   : float[B][2][C]      @ 67584   (4096)   Σ cnt_h·P_h  per (b,half,c)
//   nodesq  : float[B][C]         @ 71680   (2048)   Σ cnt·P²     per (b,c)
//   stats   : float[2][C]         @ 73728   (256)    sc2 | sh2 (exp2-folded BN affine)
//   P(bf16) : ushort[B][N][256]   @ 73984   (16 MB)
// zero region: cnt+denom+nodew+nodesq = 73728 floats = 294912 bytes

__device__ __forceinline__ ushort16 f2bf(float f) {
    uint32 u = __float_as_uint(f);
    u += 0x7fffu + ((u >> 16) & 1u);   // RNE (finite, no NaN possible here)
    return (ushort16)(u >> 16);
}
__device__ __forceinline__ float bf_lo(uint32 v) { return __uint_as_float(v << 16); }
__device__ __forceinline__ float bf_hi(uint32 v) { return __uint_as_float(v & 0xffff0000u); }

// PROVEN form (287µs session): full-occupancy flat global atomics.
// (Round-0's 64-block LDS histogram = 1 wave/SIMD on 64 CUs → latency-bound; reverted.)
__global__ __launch_bounds__(256) void k_count(const int* __restrict__ adj,
                                               int* __restrict__ cnt) {
    int i = blockIdx.x * 256 + threadIdx.x;   // 0 .. B*E*2-1
    int n = adj[i];
    int k = i & 1;
    int b = i / (E * 2);
    atomicAdd(&cnt[(b * N + n) * 2 + k], 1);
}

__global__ __launch_bounds__(256) void k_denom(const float* __restrict__ atom,
                                               const int* __restrict__ cnt,
                                               float* __restrict__ denom) {
    // grid = B*16 blocks (128 nodes each); b pinned to XCD via bid&15
    int bid = blockIdx.x;
    int b = bid & 15;
    int chunk = bid >> 4;         // 0..15
    int t = threadIdx.x;
    int ch = t & 127;             // input channel 0..127
    int sub = t >> 7;             // 0/1 : 64-node subchunk
    int half = ch >> 6;
    int f = ch & 63;
    float s = 0.f;
    int n0 = chunk * 128 + sub * 64;
    for (int j = 0; j < 64; ++j) {
        int n = n0 + j;
        float cf = (float)cnt[(b * N + n) * 2 + half];
        s = fmaf(cf, fabsf(atom[(b * N + n) * 64 + f]), s);
    }
    __shared__ float sd[256];
    sd[t] = s;
    __syncthreads();
    if (t < 128) atomicAdd(&denom[b * C + ch], sd[t] + sd[t + 128]);
}

__global__ __launch_bounds__(256, 2) void k_p(const float* __restrict__ atom,
                                              const float* __restrict__ W,
                                              const float* __restrict__ denom,
                                              const int* __restrict__ cnt,
                                              ushort16* __restrict__ P,
                                              float* __restrict__ nodew,
                                              float* __restrict__ nodesq) {
    // grid = B*32 blocks, 64 node-rows each; b = bid&15 (XCD pin matches k_out)
    // thread: (half, output chans c & c+64, row subrange sub*32..+32)
    int bid = blockIdx.x;
    int b = bid & 15;
    int chunk = bid >> 4;         // 0..31
    int t = threadIdx.x;
    int cp = t & 127;
    int half = cp >> 6;           // which P (P0/P1)
    int c = cp & 63;              // output channels c, c+64
    int sub = t >> 7;             // row subrange

    __shared__ float invd[128];
    __shared__ float A2[64 * 128];
    __shared__ float cnts[2][64];

    if (t < 128) invd[t] = 1.0f / fmaxf(denom[b * C + t], 1e-12f);
    int nbase = chunk * 64;
    if (t < 128) {
        int h = t >> 6, r = t & 63;
        cnts[h][r] = (float)cnt[(b * N + nbase + r) * 2 + h];
    }
    __syncthreads();

    // stage scaled A tile: row-major [row][lo(64)|hi(64)]
    for (int i = t; i < 64 * 128; i += 256) {
        int r = i >> 7, col = i & 127;
        float a = atom[(b * N + nbase + r) * 64 + (col & 63)];
        A2[i] = a * invd[col];
    }

    // W columns for (half, c) and (half, c+64) in registers
    float wreg0[64], wreg1[64];
#pragma unroll
    for (int f = 0; f < 64; ++f) {
        wreg0[f] = W[(half * 64 + f) * 128 + c];
        wreg1[f] = W[(half * 64 + f) * 128 + c + 64];
    }

    __syncthreads();

    float s1a = 0.f, s2a = 0.f, s1b = 0.f, s2b = 0.f;
    int r0 = sub * 32;
    for (int r = r0; r < r0 + 32; ++r) {
        const float* a = &A2[r * 128 + half * 64];
        float acc0 = 0.f, acc1 = 0.f;
#pragma unroll
        for (int f = 0; f < 64; f += 4) {
            float4 av = *(const float4*)(a + f);
            acc0 = fmaf(av.x, wreg0[f], acc0);
            acc0 = fmaf(av.y, wreg0[f + 1], acc0);
            acc0 = fmaf(av.z, wreg0[f + 2], acc0);
            acc0 = fmaf(av.w, wreg0[f + 3], acc0);
            acc1 = fmaf(av.x, wreg1[f], acc1);
            acc1 = fmaf(av.y, wreg1[f + 1], acc1);
            acc1 = fmaf(av.z, wreg1[f + 2], acc1);
            acc1 = fmaf(av.w, wreg1[f + 3], acc1);
        }
        float cw = cnts[half][r];
        s1a = fmaf(cw, acc0, s1a);
        s2a = fmaf(cw * acc0, acc0, s2a);
        s1b = fmaf(cw, acc1, s1b);
        s2b = fmaf(cw * acc1, acc1, s2b);
        // row layout: ushort[256] = [P0 ch0..127 | P1 ch0..127]
        size_t base = ((size_t)(b * N + nbase + r)) * 256 + half * 128;
        P[base + c]      = f2bf(acc0);
        P[base + c + 64] = f2bf(acc1);
    }
    atomicAdd(&nodew[b * 256 + half * 128 + c],      s1a);
    atomicAdd(&nodew[b * 256 + half * 128 + c + 64], s1b);
    atomicAdd(&nodesq[b * 128 + c],      s2a);
    atomicAdd(&nodesq[b * 128 + c + 64], s2b);
}

// 1 block, 128 threads: finalize BN affine once (was redundantly recomputed by
// all 768 k_out blocks, a serial 16-iter L2-latency chain at each block head).
// Folds 2*log2(e) so k_out's tanh is 1 - 2*rcp(exp2(d*sc2 + sh2) + 1).
__global__ __launch_bounds__(128) void k_stats(const float* __restrict__ nodew,
                                               const float* __restrict__ nodesq,
                                               const float* __restrict__ gamma,
                                               const float* __restrict__ beta,
                                               float* __restrict__ st) {
    int cch = threadIdx.x;    // 0..127
    float m = 0.f, q = 0.f;
    const float invE = 1.0f / (float)E;
#pragma unroll
    for (int b2 = 0; b2 < B; ++b2) {
        float S0 = nodew[b2 * 256 + cch];
        float S1 = nodew[b2 * 256 + 128 + cch];
        m += S0 + S1;
        // Σ_e d² = Σ cnt·P² + 2·Σ_e P0[n0]P1[n1]; cross ≈ S0·S1/E (var ≪ eps)
        q += nodesq[b2 * 128 + cch] + 2.0f * S0 * S1 * invE;
    }
    const float inv = 1.0f / (float)(B * E);
    float mean_d = m * inv;
    float var = fmaxf(q * inv - mean_d * mean_d, 0.f);
    float sc = gamma[cch] * rsqrtf(var + 1e-5f);
    float sh = beta[cch] - mean_d * sc;        // linear bias cancels in BN
    const float C2 = 2.8853900817779268f;      // 2*log2(e): exp(2x) == exp2(C2*x)
    st[cch]       = sc * C2;
    st[128 + cch] = sh * C2;
}

// PROVEN gather/store structure (287µs session): 32 lanes/edge, uint2 gathers,
// UNIT-STRIDE stores (Round-0's 16-lane/edge variant had 32B-strided 16B stores
// + nontemporal → partial-sector HBM write amplification; reverted).
// Kept vs baseline: BN affine precomputed by k_stats (no per-block 16-iter
// serial chain), exp2-folded tanh (saves mul+2 VALU per element).
__global__ __launch_bounds__(256) void k_out(const ivec2* __restrict__ adj2,
                                             const uint2* __restrict__ Pu2,
                                             const float* __restrict__ st,
                                             fvec4* __restrict__ out4) {
    // grid = 768 = 16 b * 48 chunks (512 edges each); b = bid&15 (XCD pin)
    int bid = blockIdx.x;
    int b = bid & 15;
    int chunk = bid >> 4;
    int t = threadIdx.x;
    __shared__ float ssc[128], ssh[128];
    __shared__ ivec2 eadj[512];

    int e0 = chunk * 512;
    const ivec2* ab = &adj2[(size_t)b * E + e0];
    eadj[t]       = __builtin_nontemporal_load(&ab[t]);
    eadj[t + 256] = __builtin_nontemporal_load(&ab[t + 256]);

    if (t < 128) {
        ssc[t] = st[t];
        ssh[t] = st[128 + t];
    }
    __syncthreads();

    int g = t >> 6;               // wave 0..3
    int l = t & 63;
    int esub = l >> 5;            // 2 edges per wave
    int c4 = l & 31;              // 4 channels per lane
    float sc0 = ssc[4 * c4],     sh0 = ssh[4 * c4];
    float sc1 = ssc[4 * c4 + 1], sh1 = ssh[4 * c4 + 1];
    float sc2 = ssc[4 * c4 + 2], sh2 = ssh[4 * c4 + 2];
    float sc3 = ssc[4 * c4 + 3], sh3 = ssh[4 * c4 + 3];
#pragma unroll 4
    for (int i = 0; i < 64; ++i) {
        int ei = i * 8 + g * 2 + esub;
        ivec2 nn = eadj[ei];
        uint2 v0 = Pu2[((size_t)(b * N + nn.x)) * 64 + c4];        // P0 quad
        uint2 v1 = Pu2[((size_t)(b * N + nn.y)) * 64 + 32 + c4];   // P1 quad
        float d0 = bf_lo(v0.x) + bf_lo(v1.x);
        float d1 = bf_hi(v0.x) + bf_hi(v1.x);
        float d2 = bf_lo(v0.y) + bf_lo(v1.y);
        float d3 = bf_hi(v0.y) + bf_hi(v1.y);
        float x0 = fmaf(d0, sc0, sh0);
        float x1 = fmaf(d1, sc1, sh1);
        float x2 = fmaf(d2, sc2, sh2);
        float x3 = fmaf(d3, sc3, sh3);
        // tanh(x) = 1 - 2/(exp2(x') + 1), x' = 2*log2e*x folded into sc/sh
        fvec4 o;
        o.x = fmaf(-2.0f, __builtin_amdgcn_rcpf(__builtin_amdgcn_exp2f(x0) + 1.0f), 1.0f);
        o.y = fmaf(-2.0f, __builtin_amdgcn_rcpf(__builtin_amdgcn_exp2f(x1) + 1.0f), 1.0f);
        o.z = fmaf(-2.0f, __builtin_amdgcn_rcpf(__builtin_amdgcn_exp2f(x2) + 1.0f), 1.0f);
        o.w = fmaf(-2.0f, __builtin_amdgcn_rcpf(__builtin_amdgcn_exp2f(x3) + 1.0f), 1.0f);
        __builtin_nontemporal_store(o, &out4[((size_t)(b * E + e0 + ei)) * 32 + c4]);
    }
}

extern "C" void kernel_launch(void* const* d_in, const int* in_sizes, int n_in,
                              void* d_out, int out_size, void* d_ws, size_t ws_size,
                              hipStream_t stream) {
    const float* atom  = (const float*)d_in[0];
    const int*   adj   = (const int*)d_in[1];
    const float* W     = (const float*)d_in[2];
    // d_in[3] = bias: cancels exactly in BatchNorm -> unused
    const float* gamma = (const float*)d_in[4];
    const float* beta  = (const float*)d_in[5];
    float* out = (float*)d_out;
    float* ws  = (float*)d_ws;

    int*      cnt    = (int*)ws;
    float*    denom  = ws + 65536;
    float*    nodew  = ws + 67584;
    float*    nodesq = ws + 71680;
    float*    st     = ws + 73728;
    ushort16* P      = (ushort16*)(ws + 73984);

    (void)hipMemsetAsync(d_ws, 0, 294912, stream);         // cnt+denom+nodew+nodesq
    k_count<<<3072, 256, 0, stream>>>(adj, cnt);
    k_denom<<<256,  256, 0, stream>>>(atom, cnt, denom);
    k_p    <<<512,  256, 0, stream>>>(atom, W, denom, cnt, P, nodew, nodesq);
    k_stats<<<1,    128, 0, stream>>>(nodew, nodesq, gamma, beta, st);
    k_out  <<<768,  256, 0, stream>>>((const ivec2*)adj, (const uint2*)P, st, (fvec4*)out);
}

// Round 6
// 286.715 us; speedup vs baseline: 1.1452x; 1.0107x over previous
//
#include <hip/hip_runtime.h>

#define B 16
#define N 2048
#define F 64
#define E 24576   // edges per batch (N*M, M=12)
#define C 128     // bond channels

typedef unsigned int uint32;
typedef unsigned short ushort16;
typedef float fvec4 __attribute__((ext_vector_type(4)));
typedef int   ivec2 __attribute__((ext_vector_type(2)));

// ws layout (float units):
//   cnt     : int[B][N][2]        @ 0       (65536)
//   denom   : float[B][C]         @ 65536   (2048)
//   nodew   : float[B][2][C]      @ 67584   (4096)   Σ cnt_h·P_h  per (b,half,c)
//   nodesq  : float[B][C]         @ 71680   (2048)   Σ cnt·P²     per (b,c)
//   stats   : float[2][C]         @ 73728   (256)    sc2 | sh2 (exp2-folded BN affine)
//   P(bf16) : ushort[B][N][256]   @ 73984   (16 MB)
// zero region: cnt+denom+nodew+nodesq = 73728 floats = 294912 bytes

__device__ __forceinline__ ushort16 f2bf(float f) {
    uint32 u = __float_as_uint(f);
    u += 0x7fffu + ((u >> 16) & 1u);   // RNE (finite, no NaN possible here)
    return (ushort16)(u >> 16);
}
__device__ __forceinline__ float bf_lo(uint32 v) { return __uint_as_float(v << 16); }
__device__ __forceinline__ float bf_hi(uint32 v) { return __uint_as_float(v & 0xffff0000u); }

// PROVEN form (287µs): full-occupancy flat global atomics.
// (64-block LDS histogram = 1 wave/SIMD → latency-bound regression, R0/R4.)
__global__ __launch_bounds__(256) void k_count(const int* __restrict__ adj,
                                               int* __restrict__ cnt) {
    int i = blockIdx.x * 256 + threadIdx.x;   // 0 .. B*E*2-1
    int n = adj[i];
    int k = i & 1;
    int b = i / (E * 2);
    atomicAdd(&cnt[(b * N + n) * 2 + k], 1);
}

// Restructured (R5): one thread per feature computes BOTH halves — atom loaded
// once (was 2x), cnt as int2 broadcast, 16-iter loop (was 64), grid 512 (was 256).
__global__ __launch_bounds__(256) void k_denom(const float* __restrict__ atom,
                                               const int* __restrict__ cnt,
                                               float* __restrict__ denom) {
    // grid = B*32 blocks (64 nodes each); b pinned to XCD via bid&15
    int bid = blockIdx.x;
    int b = bid & 15;
    int chunk = bid >> 4;          // 0..31
    int t = threadIdx.x;
    int f = t & 63;                // feature 0..63
    int sub = t >> 6;              // 0..3 : 16-node subchunk
    int n0 = chunk * 64 + sub * 16;
    float s0 = 0.f, s1 = 0.f;
    for (int j = 0; j < 16; ++j) {
        int n = n0 + j;
        int2 cc = *(const int2*)&cnt[(b * N + n) * 2];      // broadcast across wave
        float a = fabsf(atom[(b * N + n) * 64 + f]);        // coalesced 256B
        s0 = fmaf((float)cc.x, a, s0);
        s1 = fmaf((float)cc.y, a, s1);
    }
    __shared__ float sd[2][4][64];   // [half][sub][f]
    sd[0][sub][f] = s0;
    sd[1][sub][f] = s1;
    __syncthreads();
    if (t < 128) {
        int half = t >> 6, ff = t & 63;
        float v = (sd[half][0][ff] + sd[half][1][ff]) +
                  (sd[half][2][ff] + sd[half][3][ff]);
        atomicAdd(&denom[b * C + half * 64 + ff], v);
    }
}

__global__ __launch_bounds__(256, 2) void k_p(const float* __restrict__ atom,
                                              const float* __restrict__ W,
                                              const float* __restrict__ denom,
                                              const int* __restrict__ cnt,
                                              ushort16* __restrict__ P,
                                              float* __restrict__ nodew,
                                              float* __restrict__ nodesq) {
    // grid = B*32 blocks, 64 node-rows each; b = bid&15 (XCD pin matches k_out)
    // thread: (half, output chans c & c+64, row subrange sub*32..+32)
    int bid = blockIdx.x;
    int b = bid & 15;
    int chunk = bid >> 4;         // 0..31
    int t = threadIdx.x;
    int cp = t & 127;
    int half = cp >> 6;           // which P (P0/P1)
    int c = cp & 63;              // output channels c, c+64
    int sub = t >> 7;             // row subrange

    __shared__ float invd[128];
    __shared__ float A2[64 * 128];
    __shared__ float cnts[2][64];

    if (t < 128) invd[t] = 1.0f / fmaxf(denom[b * C + t], 1e-12f);
    int nbase = chunk * 64;
    if (t < 128) {
        int h = t >> 6, r = t & 63;
        cnts[h][r] = (float)cnt[(b * N + nbase + r) * 2 + h];
    }
    __syncthreads();

    // stage scaled A tile: row-major [row][lo(64)|hi(64)]
    for (int i = t; i < 64 * 128; i += 256) {
        int r = i >> 7, col = i & 127;
        float a = atom[(b * N + nbase + r) * 64 + (col & 63)];
        A2[i] = a * invd[col];
    }

    // W columns for (half, c) and (half, c+64) in registers
    float wreg0[64], wreg1[64];
#pragma unroll
    for (int f = 0; f < 64; ++f) {
        wreg0[f] = W[(half * 64 + f) * 128 + c];
        wreg1[f] = W[(half * 64 + f) * 128 + c + 64];
    }

    __syncthreads();

    float s1a = 0.f, s2a = 0.f, s1b = 0.f, s2b = 0.f;
    int r0 = sub * 32;
    for (int r = r0; r < r0 + 32; ++r) {
        const float* a = &A2[r * 128 + half * 64];
        float acc0 = 0.f, acc1 = 0.f;
#pragma unroll
        for (int f = 0; f < 64; f += 4) {
            float4 av = *(const float4*)(a + f);
            acc0 = fmaf(av.x, wreg0[f], acc0);
            acc0 = fmaf(av.y, wreg0[f + 1], acc0);
            acc0 = fmaf(av.z, wreg0[f + 2], acc0);
            acc0 = fmaf(av.w, wreg0[f + 3], acc0);
            acc1 = fmaf(av.x, wreg1[f], acc1);
            acc1 = fmaf(av.y, wreg1[f + 1], acc1);
            acc1 = fmaf(av.z, wreg1[f + 2], acc1);
            acc1 = fmaf(av.w, wreg1[f + 3], acc1);
        }
        float cw = cnts[half][r];
        s1a = fmaf(cw, acc0, s1a);
        s2a = fmaf(cw * acc0, acc0, s2a);
        s1b = fmaf(cw, acc1, s1b);
        s2b = fmaf(cw * acc1, acc1, s2b);
        // row layout: ushort[256] = [P0 ch0..127 | P1 ch0..127]
        size_t base = ((size_t)(b * N + nbase + r)) * 256 + half * 128;
        P[base + c]      = f2bf(acc0);
        P[base + c + 64] = f2bf(acc1);
    }
    atomicAdd(&nodew[b * 256 + half * 128 + c],      s1a);
    atomicAdd(&nodew[b * 256 + half * 128 + c + 64], s1b);
    atomicAdd(&nodesq[b * 128 + c],      s2a);
    atomicAdd(&nodesq[b * 128 + c + 64], s2b);
}

// 1 block, 128 threads: BN affine finalize, exp2-folded (neutral vs inline
// per-block compute — R5 measured — but free and removes redundant work).
__global__ __launch_bounds__(128) void k_stats(const float* __restrict__ nodew,
                                               const float* __restrict__ nodesq,
                                               const float* __restrict__ gamma,
                                               const float* __restrict__ beta,
                                               float* __restrict__ st) {
    int cch = threadIdx.x;    // 0..127
    float m = 0.f, q = 0.f;
    const float invE = 1.0f / (float)E;
#pragma unroll
    for (int b2 = 0; b2 < B; ++b2) {
        float S0 = nodew[b2 * 256 + cch];
        float S1 = nodew[b2 * 256 + 128 + cch];
        m += S0 + S1;
        // Σ_e d² = Σ cnt·P² + 2·Σ_e P0[n0]P1[n1]; cross ≈ S0·S1/E (var ≪ eps)
        q += nodesq[b2 * 128 + cch] + 2.0f * S0 * S1 * invE;
    }
    const float inv = 1.0f / (float)(B * E);
    float mean_d = m * inv;
    float var = fmaxf(q * inv - mean_d * mean_d, 0.f);
    float sc = gamma[cch] * rsqrtf(var + 1e-5f);
    float sh = beta[cch] - mean_d * sc;        // linear bias cancels in BN
    const float C2 = 2.8853900817779268f;      // 2*log2(e): exp(2x) == exp2(C2*x)
    st[cch]       = sc * C2;
    st[128 + cch] = sh * C2;
}

// PROVEN gather/store structure: 32 lanes/edge, uint2 gathers, UNIT-STRIDE
// stores (INVARIANT — R0's strided-store variant cost +40µs).
// R5 change: grid 768→1536 (256 edges/block) → 6 blocks/CU, 2x waves to hide
// L2 gather latency.
__global__ __launch_bounds__(256) void k_out(const ivec2* __restrict__ adj2,
                                             const uint2* __restrict__ Pu2,
                                             const float* __restrict__ st,
                                             fvec4* __restrict__ out4) {
    // grid = 1536 = 16 b * 96 chunks (256 edges each); b = bid&15 (XCD pin)
    int bid = blockIdx.x;
    int b = bid & 15;
    int chunk = bid >> 4;
    int t = threadIdx.x;
    __shared__ float ssc[128], ssh[128];
    __shared__ ivec2 eadj[256];

    int e0 = chunk * 256;
    const ivec2* ab = &adj2[(size_t)b * E + e0];
    eadj[t] = __builtin_nontemporal_load(&ab[t]);

    if (t < 128) {
        ssc[t] = st[t];
        ssh[t] = st[128 + t];
    }
    __syncthreads();

    int g = t >> 6;               // wave 0..3
    int l = t & 63;
    int esub = l >> 5;            // 2 edges per wave
    int c4 = l & 31;              // 4 channels per lane
    float sc0 = ssc[4 * c4],     sh0 = ssh[4 * c4];
    float sc1 = ssc[4 * c4 + 1], sh1 = ssh[4 * c4 + 1];
    float sc2 = ssc[4 * c4 + 2], sh2 = ssh[4 * c4 + 2];
    float sc3 = ssc[4 * c4 + 3], sh3 = ssh[4 * c4 + 3];
#pragma unroll 4
    for (int i = 0; i < 32; ++i) {
        int ei = i * 8 + g * 2 + esub;
        ivec2 nn = eadj[ei];
        uint2 v0 = Pu2[((size_t)(b * N + nn.x)) * 64 + c4];        // P0 quad
        uint2 v1 = Pu2[((size_t)(b * N + nn.y)) * 64 + 32 + c4];   // P1 quad
        float d0 = bf_lo(v0.x) + bf_lo(v1.x);
        float d1 = bf_hi(v0.x) + bf_hi(v1.x);
        float d2 = bf_lo(v0.y) + bf_lo(v1.y);
        float d3 = bf_hi(v0.y) + bf_hi(v1.y);
        float x0 = fmaf(d0, sc0, sh0);
        float x1 = fmaf(d1, sc1, sh1);
        float x2 = fmaf(d2, sc2, sh2);
        float x3 = fmaf(d3, sc3, sh3);
        // tanh(x) = 1 - 2/(exp2(x') + 1), x' = 2*log2e*x folded into sc/sh
        fvec4 o;
        o.x = fmaf(-2.0f, __builtin_amdgcn_rcpf(__builtin_amdgcn_exp2f(x0) + 1.0f), 1.0f);
        o.y = fmaf(-2.0f, __builtin_amdgcn_rcpf(__builtin_amdgcn_exp2f(x1) + 1.0f), 1.0f);
        o.z = fmaf(-2.0f, __builtin_amdgcn_rcpf(__builtin_amdgcn_exp2f(x2) + 1.0f), 1.0f);
        o.w = fmaf(-2.0f, __builtin_amdgcn_rcpf(__builtin_amdgcn_exp2f(x3) + 1.0f), 1.0f);
        __builtin_nontemporal_store(o, &out4[((size_t)(b * E + e0 + ei)) * 32 + c4]);
    }
}

extern "C" void kernel_launch(void* const* d_in, const int* in_sizes, int n_in,
                              void* d_out, int out_size, void* d_ws, size_t ws_size,
                              hipStream_t stream) {
    const float* atom  = (const float*)d_in[0];
    const int*   adj   = (const int*)d_in[1];
    const float* W     = (const float*)d_in[2];
    // d_in[3] = bias: cancels exactly in BatchNorm -> unused
    const float* gamma = (const float*)d_in[4];
    const float* beta  = (const float*)d_in[5];
    float* out = (float*)d_out;
    float* ws  = (float*)d_ws;

    int*      cnt    = (int*)ws;
    float*    denom  = ws + 65536;
    float*    nodew  = ws + 67584;
    float*    nodesq = ws + 71680;
    float*    st     = ws + 73728;
    ushort16* P      = (ushort16*)(ws + 73984);

    (void)hipMemsetAsync(d_ws, 0, 294912, stream);         // cnt+denom+nodew+nodesq
    k_count<<<3072, 256, 0, stream>>>(adj, cnt);
    k_denom<<<512,  256, 0, stream>>>(atom, cnt, denom);
    k_p    <<<512,  256, 0, stream>>>(atom, W, denom, cnt, P, nodew, nodesq);
    k_stats<<<1,    128, 0, stream>>>(nodew, nodesq, gamma, beta, st);
    k_out  <<<1536, 256, 0, stream>>>((const ivec2*)adj, (const uint2*)P, st, (fvec4*)out);
}

// Round 7
// 281.608 us; speedup vs baseline: 1.1659x; 1.0181x over previous
//
#include <hip/hip_runtime.h>

#define B 16
#define N 2048
#define F 64
#define E 24576   // edges per batch (N*M, M=12)
#define C 128     // bond channels

typedef unsigned int uint32;
typedef unsigned short ushort16;
typedef float fvec4 __attribute__((ext_vector_type(4)));
typedef int   ivec2 __attribute__((ext_vector_type(2)));

// ws layout (float units):
//   cnt     : int[B][N][2]        @ 0       (65536)   <- memset (262144 B)
//   denom   : float[B][C]         @ 65536   (2048)  \
//   nodew   : float[B][2][C]      @ 67584   (4096)   } zeroed by k_count blocks 0-7
//   nodesq  : float[B][C]         @ 71680   (2048)  /
//   P(bf16) : ushort[B][N][256]   @ 73984   (16 MB)

__device__ __forceinline__ ushort16 f2bf(float f) {
    uint32 u = __float_as_uint(f);
    u += 0x7fffu + ((u >> 16) & 1u);   // RNE (finite, no NaN possible here)
    return (ushort16)(u >> 16);
}
__device__ __forceinline__ float bf_lo(uint32 v) { return __uint_as_float(v << 16); }
__device__ __forceinline__ float bf_hi(uint32 v) { return __uint_as_float(v & 0xffff0000u); }

// PROVEN form (287µs): full-occupancy flat global atomics.
// (64-block LDS histogram = 1 wave/SIMD → latency-bound regression, R0/R4.)
// R6: blocks 0-7 also zero the 8192-float accumulator tail (replaces 11% of
// the memset; completes before k_denom/k_p launch -> safe).
__global__ __launch_bounds__(256) void k_count(const int* __restrict__ adj,
                                               int* __restrict__ cnt,
                                               float* __restrict__ ztail) {
    int bid = blockIdx.x;
    int t = threadIdx.x;
    if (bid < 8) {
        fvec4 z = {0.f, 0.f, 0.f, 0.f};
        *(fvec4*)&ztail[(bid * 256 + t) * 4] = z;   // 8*256*4 = 8192 floats
    }
    int i = bid * 256 + t;        // 0 .. B*E*2-1
    int n = adj[i];
    int k = i & 1;
    int b = i / (E * 2);
    atomicAdd(&cnt[(b * N + n) * 2 + k], 1);
}

// R5 form: one thread per feature computes BOTH halves — atom loaded once,
// cnt as int2 broadcast, 16-iter loop, grid 512.
__global__ __launch_bounds__(256) void k_denom(const float* __restrict__ atom,
                                               const int* __restrict__ cnt,
                                               float* __restrict__ denom) {
    // grid = B*32 blocks (64 nodes each); b pinned to XCD via bid&15
    int bid = blockIdx.x;
    int b = bid & 15;
    int chunk = bid >> 4;          // 0..31
    int t = threadIdx.x;
    int f = t & 63;                // feature 0..63
    int sub = t >> 6;              // 0..3 : 16-node subchunk
    int n0 = chunk * 64 + sub * 16;
    float s0 = 0.f, s1 = 0.f;
    for (int j = 0; j < 16; ++j) {
        int n = n0 + j;
        int2 cc = *(const int2*)&cnt[(b * N + n) * 2];      // broadcast across wave
        float a = fabsf(atom[(b * N + n) * 64 + f]);        // coalesced 256B
        s0 = fmaf((float)cc.x, a, s0);
        s1 = fmaf((float)cc.y, a, s1);
    }
    __shared__ float sd[2][4][64];   // [half][sub][f]
    sd[0][sub][f] = s0;
    sd[1][sub][f] = s1;
    __syncthreads();
    if (t < 128) {
        int half = t >> 6, ff = t & 63;
        float v = (sd[half][0][ff] + sd[half][1][ff]) +
                  (sd[half][2][ff] + sd[half][3][ff]);
        atomicAdd(&denom[b * C + half * 64 + ff], v);
    }
}

__global__ __launch_bounds__(256, 2) void k_p(const float* __restrict__ atom,
                                              const float* __restrict__ W,
                                              const float* __restrict__ denom,
                                              const int* __restrict__ cnt,
                                              ushort16* __restrict__ P,
                                              float* __restrict__ nodew,
                                              float* __restrict__ nodesq) {
    // grid = B*32 blocks, 64 node-rows each; b = bid&15 (XCD pin matches k_out)
    // thread: (half, output chans c & c+64, row subrange sub*32..+32)
    int bid = blockIdx.x;
    int b = bid & 15;
    int chunk = bid >> 4;         // 0..31
    int t = threadIdx.x;
    int cp = t & 127;
    int half = cp >> 6;           // which P (P0/P1)
    int c = cp & 63;              // output channels c, c+64
    int sub = t >> 7;             // row subrange

    __shared__ float invd[128];
    __shared__ float A2[64 * 128];
    __shared__ float cnts[2][64];

    if (t < 128) invd[t] = 1.0f / fmaxf(denom[b * C + t], 1e-12f);
    int nbase = chunk * 64;
    if (t < 128) {
        int h = t >> 6, r = t & 63;
        cnts[h][r] = (float)cnt[(b * N + nbase + r) * 2 + h];
    }
    __syncthreads();

    // stage scaled A tile: row-major [row][lo(64)|hi(64)]
    for (int i = t; i < 64 * 128; i += 256) {
        int r = i >> 7, col = i & 127;
        float a = atom[(b * N + nbase + r) * 64 + (col & 63)];
        A2[i] = a * invd[col];
    }

    // W columns for (half, c) and (half, c+64) in registers
    float wreg0[64], wreg1[64];
#pragma unroll
    for (int f = 0; f < 64; ++f) {
        wreg0[f] = W[(half * 64 + f) * 128 + c];
        wreg1[f] = W[(half * 64 + f) * 128 + c + 64];
    }

    __syncthreads();

    float s1a = 0.f, s2a = 0.f, s1b = 0.f, s2b = 0.f;
    int r0 = sub * 32;
    for (int r = r0; r < r0 + 32; ++r) {
        const float* a = &A2[r * 128 + half * 64];
        float acc0 = 0.f, acc1 = 0.f;
#pragma unroll
        for (int f = 0; f < 64; f += 4) {
            float4 av = *(const float4*)(a + f);
            acc0 = fmaf(av.x, wreg0[f], acc0);
            acc0 = fmaf(av.y, wreg0[f + 1], acc0);
            acc0 = fmaf(av.z, wreg0[f + 2], acc0);
            acc0 = fmaf(av.w, wreg0[f + 3], acc0);
            acc1 = fmaf(av.x, wreg1[f], acc1);
            acc1 = fmaf(av.y, wreg1[f + 1], acc1);
            acc1 = fmaf(av.z, wreg1[f + 2], acc1);
            acc1 = fmaf(av.w, wreg1[f + 3], acc1);
        }
        float cw = cnts[half][r];
        s1a = fmaf(cw, acc0, s1a);
        s2a = fmaf(cw * acc0, acc0, s2a);
        s1b = fmaf(cw, acc1, s1b);
        s2b = fmaf(cw * acc1, acc1, s2b);
        // row layout: ushort[256] = [P0 ch0..127 | P1 ch0..127]
        size_t base = ((size_t)(b * N + nbase + r)) * 256 + half * 128;
        P[base + c]      = f2bf(acc0);
        P[base + c + 64] = f2bf(acc1);
    }
    atomicAdd(&nodew[b * 256 + half * 128 + c],      s1a);
    atomicAdd(&nodew[b * 256 + half * 128 + c + 64], s1b);
    atomicAdd(&nodesq[b * 128 + c],      s2a);
    atomicAdd(&nodesq[b * 128 + c + 64], s2b);
}

// PROVEN gather/store structure: 32 lanes/edge, uint2 gathers, UNIT-STRIDE
// stores (INVARIANT — R0's strided-store variant cost +40µs). Grid 1536
// (256 edges/block, 6 blocks/CU). R6: BN finalize inlined in prologue
// (separate k_stats measured neutral; inlining saves one dispatch gap).
__global__ __launch_bounds__(256) void k_out(const ivec2* __restrict__ adj2,
                                             const uint2* __restrict__ Pu2,
                                             const float* __restrict__ nodew,
                                             const float* __restrict__ nodesq,
                                             const float* __restrict__ gamma,
                                             const float* __restrict__ beta,
                                             fvec4* __restrict__ out4) {
    // grid = 1536 = 16 b * 96 chunks (256 edges each); b = bid&15 (XCD pin)
    int bid = blockIdx.x;
    int b = bid & 15;
    int chunk = bid >> 4;
    int t = threadIdx.x;
    __shared__ float ssc[128], ssh[128];
    __shared__ ivec2 eadj[256];

    int e0 = chunk * 256;
    const ivec2* ab = &adj2[(size_t)b * E + e0];
    eadj[t] = __builtin_nontemporal_load(&ab[t]);

    if (t < 128) {
        // per-block redundant BN finalize (L2-resident 6KB; unrolled = 2
        // latency rounds, hidden under other blocks' streams)
        int cch = t;
        float m = 0.f, q = 0.f;
        const float invE = 1.0f / (float)E;
#pragma unroll
        for (int b2 = 0; b2 < B; ++b2) {
            float S0 = nodew[b2 * 256 + cch];
            float S1 = nodew[b2 * 256 + 128 + cch];
            m += S0 + S1;
            // Σ_e d² = Σ cnt·P² + 2·Σ_e P0[n0]P1[n1]; cross ≈ S0·S1/E (var ≪ eps)
            q += nodesq[b2 * 128 + cch] + 2.0f * S0 * S1 * invE;
        }
        const float inv = 1.0f / (float)(B * E);
        float mean_d = m * inv;
        float var = fmaxf(q * inv - mean_d * mean_d, 0.f);
        float sc = gamma[cch] * rsqrtf(var + 1e-5f);
        float sh = beta[cch] - mean_d * sc;        // linear bias cancels in BN
        const float C2 = 2.8853900817779268f;      // 2*log2(e): exp(2x)==exp2(C2*x)
        ssc[cch] = sc * C2;
        ssh[cch] = sh * C2;
    }
    __syncthreads();

    int g = t >> 6;               // wave 0..3
    int l = t & 63;
    int esub = l >> 5;            // 2 edges per wave
    int c4 = l & 31;              // 4 channels per lane
    float sc0 = ssc[4 * c4],     sh0 = ssh[4 * c4];
    float sc1 = ssc[4 * c4 + 1], sh1 = ssh[4 * c4 + 1];
    float sc2 = ssc[4 * c4 + 2], sh2 = ssh[4 * c4 + 2];
    float sc3 = ssc[4 * c4 + 3], sh3 = ssh[4 * c4 + 3];
#pragma unroll 4
    for (int i = 0; i < 32; ++i) {
        int ei = i * 8 + g * 2 + esub;
        ivec2 nn = eadj[ei];
        uint2 v0 = Pu2[((size_t)(b * N + nn.x)) * 64 + c4];        // P0 quad
        uint2 v1 = Pu2[((size_t)(b * N + nn.y)) * 64 + 32 + c4];   // P1 quad
        float d0 = bf_lo(v0.x) + bf_lo(v1.x);
        float d1 = bf_hi(v0.x) + bf_hi(v1.x);
        float d2 = bf_lo(v0.y) + bf_lo(v1.y);
        float d3 = bf_hi(v0.y) + bf_hi(v1.y);
        float x0 = fmaf(d0, sc0, sh0);
        float x1 = fmaf(d1, sc1, sh1);
        float x2 = fmaf(d2, sc2, sh2);
        float x3 = fmaf(d3, sc3, sh3);
        // tanh(x) = 1 - 2/(exp2(x') + 1), x' = 2*log2e*x folded into sc/sh
        fvec4 o;
        o.x = fmaf(-2.0f, __builtin_amdgcn_rcpf(__builtin_amdgcn_exp2f(x0) + 1.0f), 1.0f);
        o.y = fmaf(-2.0f, __builtin_amdgcn_rcpf(__builtin_amdgcn_exp2f(x1) + 1.0f), 1.0f);
        o.z = fmaf(-2.0f, __builtin_amdgcn_rcpf(__builtin_amdgcn_exp2f(x2) + 1.0f), 1.0f);
        o.w = fmaf(-2.0f, __builtin_amdgcn_rcpf(__builtin_amdgcn_exp2f(x3) + 1.0f), 1.0f);
        __builtin_nontemporal_store(o, &out4[((size_t)(b * E + e0 + ei)) * 32 + c4]);
    }
}

extern "C" void kernel_launch(void* const* d_in, const int* in_sizes, int n_in,
                              void* d_out, int out_size, void* d_ws, size_t ws_size,
                              hipStream_t stream) {
    const float* atom  = (const float*)d_in[0];
    const int*   adj   = (const int*)d_in[1];
    const float* W     = (const float*)d_in[2];
    // d_in[3] = bias: cancels exactly in BatchNorm -> unused
    const float* gamma = (const float*)d_in[4];
    const float* beta  = (const float*)d_in[5];
    float* out = (float*)d_out;
    float* ws  = (float*)d_ws;

    int*      cnt    = (int*)ws;
    float*    denom  = ws + 65536;
    float*    nodew  = ws + 67584;
    float*    nodesq = ws + 71680;
    ushort16* P      = (ushort16*)(ws + 73984);

    (void)hipMemsetAsync(d_ws, 0, 262144, stream);          // cnt only
    k_count<<<3072, 256, 0, stream>>>(adj, cnt, ws + 65536); // + zeros 8192-float tail
    k_denom<<<512,  256, 0, stream>>>(atom, cnt, denom);
    k_p    <<<512,  256, 0, stream>>>(atom, W, denom, cnt, P, nodew, nodesq);
    k_out  <<<1536, 256, 0, stream>>>((const ivec2*)adj, (const uint2*)P,
                                      nodew, nodesq, gamma, beta, (fvec4*)out);
}